// Round 3
// baseline (316.213 us; speedup 1.0000x reference)
//
#include <hip/hip_runtime.h>
#include <math.h>

// Sparsemax over rows: out = max(z - tau, 0), tau s.t. sum(max(z - tau, 0)) = 1.
//
// ONE WAVE PER ROW: 4096 fp32 = 64 values/lane in registers. Zero block
// barriers, zero LDS, zero atomics -- waves run fully independently, so
// different rows' load/compute/store phases overlap on each CU.
//
// tau via Michelot's algorithm seeded at t0 = zmax-1 (t0 <= tau* always, and
// {z > t0} is a superset of the support): iterate
//     tau <- (sum_{z>tau} z - 1) / |{z>tau}|
// until the support count stabilizes. Threshold is monotone non-decreasing,
// support shrinks monotonically, terminates at the EXACT tau* (typically
// 3-4 iterations for Gaussian rows). Uniform branch -> no divergence.

constexpr int S   = 4096;
constexpr int TPB = 256;
constexpr int NW  = TPB / 64;   // 4 waves (= 4 rows) per block
constexpr int VPL = S / 64;     // 64 values per lane
constexpr int NC  = VPL / 4;    // 16 float4 chunks per lane

#define NEGBIG (-1e30f)

__global__ __launch_bounds__(TPB) void sparsemax_kernel(
    const float* __restrict__ scores,
    const int*   __restrict__ mask,
    float*       __restrict__ out)
{
    const int tid  = threadIdx.x;
    const int lane = tid & 63;
    const int wid  = tid >> 6;
    const int row  = blockIdx.x * NW + wid;

    const float4* srow4 = reinterpret_cast<const float4*>(scores + (size_t)row * S);
    const int4*   mrow4 = reinterpret_cast<const int4*>(mask + (size_t)row * S);
    float4*       orow4 = reinterpret_cast<float4*>(out + (size_t)row * S);

    // ---- load row: 16 float4 + 16 int4 per lane, coalesced (chunk-major) ----
    float z[VPL];
    #pragma unroll
    for (int c = 0; c < NC; ++c) {
        const float4 s4 = srow4[c * 64 + lane];
        const int4   m4 = mrow4[c * 64 + lane];
        z[c * 4 + 0] = m4.x ? s4.x : NEGBIG;
        z[c * 4 + 1] = m4.y ? s4.y : NEGBIG;
        z[c * 4 + 2] = m4.z ? s4.z : NEGBIG;
        z[c * 4 + 3] = m4.w ? s4.w : NEGBIG;
    }

    // ---- row max: local 64 + wave butterfly ----
    float m = z[0];
    #pragma unroll
    for (int j = 1; j < VPL; ++j) m = fmaxf(m, z[j]);
    #pragma unroll
    for (int o = 1; o < 64; o <<= 1) m = fmaxf(m, __shfl_xor(m, o, 64));
    const float zmax = m;

    // ---- Michelot iteration to exact tau ----
    float t = zmax - 1.0f;
    int cprev = -1;
    #pragma unroll 1
    for (int it = 0; it < 40; ++it) {
        float s = 0.0f;
        int   c = 0;
        #pragma unroll
        for (int j = 0; j < VPL; ++j) {
            const bool in = z[j] > t;
            s += in ? z[j] : 0.0f;
            c += in ? 1 : 0;
        }
        #pragma unroll
        for (int o = 1; o < 64; o <<= 1) {
            s += __shfl_xor(s, o, 64);
            c += __shfl_xor(c, o, 64);
        }
        if (c == cprev) break;          // support stable -> t is exact tau*
        t = (s - 1.0f) / (float)c;      // c >= 1 always (zmax > zmax-1)
        cprev = c;
    }
    const float tau = t;

    // ---- write out = max(z - tau, 0) ----
    #pragma unroll
    for (int c = 0; c < NC; ++c) {
        float4 o4;
        o4.x = fmaxf(z[c * 4 + 0] - tau, 0.0f);
        o4.y = fmaxf(z[c * 4 + 1] - tau, 0.0f);
        o4.z = fmaxf(z[c * 4 + 2] - tau, 0.0f);
        o4.w = fmaxf(z[c * 4 + 3] - tau, 0.0f);
        orow4[c * 64 + lane] = o4;
    }
}

extern "C" void kernel_launch(void* const* d_in, const int* in_sizes, int n_in,
                              void* d_out, int out_size, void* d_ws, size_t ws_size,
                              hipStream_t stream) {
    const float* scores = (const float*)d_in[0];
    const int*   mask   = (const int*)d_in[1];
    float*       out    = (float*)d_out;
    const int B = in_sizes[0] / S;  // 8192
    sparsemax_kernel<<<dim3(B / NW), dim3(TPB), 0, stream>>>(scores, mask, out);
}

// Round 4
// 315.815 us; speedup vs baseline: 1.0013x; 1.0013x over previous
//
#include <hip/hip_runtime.h>
#include <math.h>

// Sparsemax over rows: out = max(z - tau, 0), tau s.t. sum(max(z - tau, 0)) = 1.
//
// ONE WAVE PER ROW: 4096 fp32 = 64 values/lane in registers. Zero block
// barriers, zero LDS, zero atomics.
//
// ROUND 4 CHANGE (single variable): __launch_bounds__(256, 4).
// Round 3's __launch_bounds__(256) let the compiler target 8 waves/EU ->
// ~64-VGPR cap -> z[64] spilled to scratch (VGPR_Count=60 proved it), and
// ~1 GB of scratch reload traffic through L3 was the 120 us wall.
// min 4 waves/EU -> 128-VGPR budget -> z[] register-resident.
//
// tau via Michelot's algorithm seeded at t0 = zmax-1 (t0 <= tau*, and
// {z > t0} is a superset of the support): iterate
//     tau <- (sum_{z>tau} z - 1) / |{z>tau}|
// until the support count stabilizes -> EXACT tau (typically 3-4 iterations
// for Gaussian rows). Uniform branch -> no divergence.

constexpr int S   = 4096;
constexpr int TPB = 256;
constexpr int NW  = TPB / 64;   // 4 waves (= 4 rows) per block
constexpr int VPL = S / 64;     // 64 values per lane
constexpr int NC  = VPL / 4;    // 16 float4 chunks per lane

#define NEGBIG (-1e30f)

__global__ __launch_bounds__(TPB, 4) void sparsemax_kernel(
    const float* __restrict__ scores,
    const int*   __restrict__ mask,
    float*       __restrict__ out)
{
    const int tid  = threadIdx.x;
    const int lane = tid & 63;
    const int wid  = tid >> 6;
    const int row  = blockIdx.x * NW + wid;

    const float4* srow4 = reinterpret_cast<const float4*>(scores + (size_t)row * S);
    const int4*   mrow4 = reinterpret_cast<const int4*>(mask + (size_t)row * S);
    float4*       orow4 = reinterpret_cast<float4*>(out + (size_t)row * S);

    // ---- load row: 16 float4 + 16 int4 per lane, coalesced (chunk-major) ----
    float z[VPL];
    #pragma unroll
    for (int c = 0; c < NC; ++c) {
        const float4 s4 = srow4[c * 64 + lane];
        const int4   m4 = mrow4[c * 64 + lane];
        z[c * 4 + 0] = m4.x ? s4.x : NEGBIG;
        z[c * 4 + 1] = m4.y ? s4.y : NEGBIG;
        z[c * 4 + 2] = m4.z ? s4.z : NEGBIG;
        z[c * 4 + 3] = m4.w ? s4.w : NEGBIG;
    }

    // ---- row max: local pairwise tree + wave butterfly ----
    float m = fmaxf(z[0], z[1]);
    #pragma unroll
    for (int j = 2; j < VPL; ++j) m = fmaxf(m, z[j]);
    #pragma unroll
    for (int o = 1; o < 64; o <<= 1) m = fmaxf(m, __shfl_xor(m, o, 64));
    const float zmax = m;

    // ---- Michelot iteration to exact tau ----
    float t = zmax - 1.0f;
    int cprev = -1;
    #pragma unroll 1
    for (int it = 0; it < 40; ++it) {
        float s = 0.0f;
        int   c = 0;
        #pragma unroll
        for (int j = 0; j < VPL; ++j) {
            const bool in = z[j] > t;
            s += in ? z[j] : 0.0f;
            c += in ? 1 : 0;
        }
        #pragma unroll
        for (int o = 1; o < 64; o <<= 1) {
            s += __shfl_xor(s, o, 64);
            c += __shfl_xor(c, o, 64);
        }
        if (c == cprev) break;          // support stable -> t is exact tau*
        t = (s - 1.0f) / (float)c;      // c >= 1 always (zmax > zmax-1)
        cprev = c;
    }
    const float tau = t;

    // ---- write out = max(z - tau, 0) ----
    #pragma unroll
    for (int c = 0; c < NC; ++c) {
        float4 o4;
        o4.x = fmaxf(z[c * 4 + 0] - tau, 0.0f);
        o4.y = fmaxf(z[c * 4 + 1] - tau, 0.0f);
        o4.z = fmaxf(z[c * 4 + 2] - tau, 0.0f);
        o4.w = fmaxf(z[c * 4 + 3] - tau, 0.0f);
        orow4[c * 64 + lane] = o4;
    }
}

extern "C" void kernel_launch(void* const* d_in, const int* in_sizes, int n_in,
                              void* d_out, int out_size, void* d_ws, size_t ws_size,
                              hipStream_t stream) {
    const float* scores = (const float*)d_in[0];
    const int*   mask   = (const int*)d_in[1];
    float*       out    = (float*)d_out;
    const int B = in_sizes[0] / S;  // 8192
    sparsemax_kernel<<<dim3(B / NW), dim3(TPB), 0, stream>>>(scores, mask, out);
}